// Round 4
// baseline (813.965 us; speedup 1.0000x reference)
//
#include <hip/hip_runtime.h>
#include <hip/hip_fp16.h>

#define NB 8
#define NC 512
#define NK 128   // key_dim C2
#define NP 128   // positions per attention row (H = W = 128)
#define NHW 16384

typedef unsigned short u16;
typedef unsigned int u32;
typedef float f32x4 __attribute__((ext_vector_type(4)));
typedef _Float16 f16x8 __attribute__((ext_vector_type(8)));

__device__ __forceinline__ u16 f2h(float f) { return __half_as_ushort(__float2half(f)); }
__device__ __forceinline__ float h2f(u16 u) { return __half2float(__ushort_as_half(u)); }

// ---------------- weights fp32 -> fp16, concatenated [wq;wk] row-major ----------------
__global__ __launch_bounds__(256) void wconv_kernel(const float* __restrict__ wq,
                                                    const float* __restrict__ wk,
                                                    u16* __restrict__ wh) {
    int row = blockIdx.x;  // 0..255
    const float* src = (row < 128) ? (wq + (size_t)row * NC) : (wk + (size_t)(row - 128) * NC);
    int t = threadIdx.x;
    float2 v = *(const float2*)(src + t * 2);
    ushort2 o; o.x = f2h(v.x); o.y = f2h(v.y);
    *(ushort2*)(wh + (size_t)row * NC + t * 2) = o;
}

// ---------------- x fp32 [plane][h][w] -> xt fp16 [plane][w][h] ----------------
__global__ __launch_bounds__(256) void convtr_kernel(const float* __restrict__ x,
                                                     u16* __restrict__ xt) {
    __shared__ u16 ts[32][36];
    int plane = blockIdx.y;
    int tile  = blockIdx.x;
    int h0 = (tile >> 2) * 32, w0 = (tile & 3) * 32;
    const float* ip = x + (size_t)plane * NHW;
    u16* op = xt + (size_t)plane * NHW;
    int r  = threadIdx.x >> 3;
    int c4 = (threadIdx.x & 7) * 4;
    float4 v = *(const float4*)(ip + (h0 + r) * NP + w0 + c4);
    ts[r][c4 + 0] = f2h(v.x); ts[r][c4 + 1] = f2h(v.y);
    ts[r][c4 + 2] = f2h(v.z); ts[r][c4 + 3] = f2h(v.w);
    __syncthreads();
    ushort4 o;
    o.x = ts[c4 + 0][r]; o.y = ts[c4 + 1][r]; o.z = ts[c4 + 2][r]; o.w = ts[c4 + 3][r];
    *(ushort4*)(op + (w0 + r) * NP + h0 + c4) = o;
}

// ---------------- fused q+k projection via MFMA (v2) ----------------
// A (x^T tile) staged in LDS double-buffered with XOR swizzle; B (weights fp16)
// read directly from global (L2-resident). Epilogue bounces through LDS for
// coalesced uint4 stores. q,k: [b][p][c2] fp16.
#define XROW 40   // u16 stride of one p-row in Xt2 (80 B, 16B-aligned)
__device__ __forceinline__ int xt2_off(int p, int cw) {
    // cw = data word index 0..15 (u16 pair); swizzle 4-word blocks by p>>3
    int sw = ((p >> 3) & 3) << 2;
    return p * XROW + 2 * (cw ^ sw);
}

__global__ __launch_bounds__(256) void proj_kernel(const float* __restrict__ x,
                                                   const u16* __restrict__ wh,
                                                   const float* __restrict__ bq,
                                                   const float* __restrict__ bk,
                                                   u16* __restrict__ q,
                                                   u16* __restrict__ k) {
    __shared__ __align__(16) u16 Xt2[2][128 * XROW];
    int b  = blockIdx.y;
    int p0 = blockIdx.x * 128;
    int tid = threadIdx.x;
    int lane = tid & 63, w = tid >> 6;
    int ln = lane & 15, g = lane >> 4;
    int wm = w >> 1, wn = w & 1;

    // per-thread bias for the 8 oc's this thread owns
    float biasv[8];
#pragma unroll
    for (int nf = 0; nf < 8; nf++) {
        int oc = wn * 128 + nf * 16 + ln;
        biasv[nf] = (oc < 128) ? bq[oc] : bk[oc - 128];
    }

    f32x4 acc[4][8];
#pragma unroll
    for (int mf = 0; mf < 4; mf++)
#pragma unroll
        for (int nf = 0; nf < 8; nf++) acc[mf][nf] = 0.0f;

    // staging: thread handles channel rows (c0+2i, c0+2i+1), 8 pixels
    int si  = tid >> 4;          // 0..15
    int spx = (tid & 15) * 8;

#define STAGE(buf, c0)                                                                  \
    {                                                                                   \
        const float* xa = x + ((size_t)(b * NC + (c0) + 2 * si)) * NHW + p0 + spx;      \
        const float* xb = xa + NHW;                                                     \
        float4 a0 = *(const float4*)xa, a1 = *(const float4*)(xa + 4);                  \
        float4 b0 = *(const float4*)xb, b1 = *(const float4*)(xb + 4);                  \
        float av[8] = {a0.x, a0.y, a0.z, a0.w, a1.x, a1.y, a1.z, a1.w};                 \
        float bv[8] = {b0.x, b0.y, b0.z, b0.w, b1.x, b1.y, b1.z, b1.w};                 \
        _Pragma("unroll") for (int j = 0; j < 8; j++) {                                 \
            ushort2 pk;                                                                 \
            pk.x = f2h(av[j]); pk.y = f2h(bv[j]);                                       \
            *(ushort2*)&Xt2[buf][xt2_off(spx + j, si)] = pk;                            \
        }                                                                               \
    }

    STAGE(0, 0);
    __syncthreads();
    for (int t = 0; t < 16; ++t) {
        int c0 = t * 32;
        if (t < 15) STAGE((t + 1) & 1, c0 + 32);
        // B fragments straight from global (L2)
        f16x8 bf[8];
#pragma unroll
        for (int nf = 0; nf < 8; nf++)
            bf[nf] = *(const f16x8*)&wh[((size_t)(wn * 128 + nf * 16 + ln)) * NC + c0 + g * 8];
        // A fragments from LDS (swizzled)
        f16x8 af[4];
#pragma unroll
        for (int mf = 0; mf < 4; mf++)
            af[mf] = *(const f16x8*)&Xt2[t & 1][xt2_off(wm * 64 + mf * 16 + ln, g * 4)];
#pragma unroll
        for (int mf = 0; mf < 4; mf++)
#pragma unroll
            for (int nf = 0; nf < 8; nf++)
                acc[mf][nf] = __builtin_amdgcn_mfma_f32_16x16x32_f16(af[mf], bf[nf], acc[mf][nf], 0, 0, 0);
        __syncthreads();
    }
#undef STAGE

    // ---- epilogue: LDS bounce for coalesced stores ----
    u16* Ep = &Xt2[0][0];      // 128 rows x 72 u16 = 9216 u16 (fits in 10240)
#pragma unroll 1
    for (int oh = 0; oh < 4; oh++) {
        int wn_sel = oh >> 1;
        int nf0 = (oh & 1) * 4;
        if (wn == wn_sel) {
#pragma unroll
            for (int mf = 0; mf < 4; mf++)
#pragma unroll
                for (int nfi = 0; nfi < 4; nfi++) {
                    int nf = nf0 + nfi;
#pragma unroll
                    for (int rg = 0; rg < 4; rg++) {
                        int prow = wm * 64 + mf * 16 + g * 4 + rg;
                        Ep[prow * 72 + nfi * 16 + ln] = f2h(acc[mf][nf][rg] + biasv[nf]);
                    }
                }
        }
        __syncthreads();
        {
            int p = tid >> 1, half = tid & 1;
            u16* dst = (oh < 2 ? q : k) + ((size_t)(b * NHW + p0 + p)) * NK + (oh & 1) * 64 + half * 32;
            const u16* srcl = &Ep[p * 72 + half * 32];
#pragma unroll
            for (int e = 0; e < 4; e++)
                *(uint4*)(dst + e * 8) = *(const uint4*)(srcl + e * 8);
        }
        __syncthreads();
    }
}

// ---------------- axis attention via MFMA ----------------
// TR=0 (W-pass): r=h, Q/K rows contiguous, V = x fp32, out = float*
// TR=1 (H-pass): r=w, Q/K rows strided, V = xt fp16, out = oht fp16
template <int TR>
__global__ __launch_bounds__(256) void attn_kernel(const u16* __restrict__ q,
                                                   const u16* __restrict__ k,
                                                   const void* __restrict__ vsrc,
                                                   void* __restrict__ osrc) {
    __shared__ __align__(16) u16 smem[2 * 128 * 136];
    __shared__ float redmax[256];
    __shared__ float redsum[256];
    u16* Ks = smem;
    u16* Qs = smem + 128 * 136;
    u16* Al = smem;
    u16* Vl = smem + 128 * 136;

    int r = blockIdx.x, b = blockIdx.y;
    int tid = threadIdx.x;
    int lane = tid & 63, w = tid >> 6;
    int ln = lane & 15, g = lane >> 4;

    const size_t base = TR ? ((size_t)b * NHW + r) * NK : ((size_t)b * NHW + (size_t)r * NP) * NK;
    const int qrs = TR ? NP * NK : NK;

    {
        int j = tid >> 1, hf = tid & 1;
        const u16* qp2 = q + base + (size_t)j * qrs + hf * 64;
        const u16* kp2 = k + base + (size_t)j * qrs + hf * 64;
#pragma unroll
        for (int e = 0; e < 8; e++) {
            *(uint4*)&Qs[j * 136 + hf * 64 + e * 8] = *(const uint4*)(qp2 + e * 8);
            *(uint4*)&Ks[j * 136 + hf * 64 + e * 8] = *(const uint4*)(kp2 + e * 8);
        }
    }
    __syncthreads();

    int wj = w >> 1, wi = w & 1;
    f32x4 e[4][4];
#pragma unroll
    for (int mf = 0; mf < 4; mf++)
#pragma unroll
        for (int nf = 0; nf < 4; nf++) e[mf][nf] = 0.0f;
#pragma unroll
    for (int ks = 0; ks < 4; ks++) {
        f16x8 qa[4], kb[4];
#pragma unroll
        for (int mf = 0; mf < 4; mf++)
            qa[mf] = *(const f16x8*)&Qs[(wj * 64 + mf * 16 + ln) * 136 + ks * 32 + g * 8];
#pragma unroll
        for (int nf = 0; nf < 4; nf++)
            kb[nf] = *(const f16x8*)&Ks[(wi * 64 + nf * 16 + ln) * 136 + ks * 32 + g * 8];
#pragma unroll
        for (int mf = 0; mf < 4; mf++)
#pragma unroll
            for (int nf = 0; nf < 4; nf++)
                e[mf][nf] = __builtin_amdgcn_mfma_f32_16x16x32_f16(qa[mf], kb[nf], e[mf][nf], 0, 0, 0);
    }

    float pm[4];
#pragma unroll
    for (int nf = 0; nf < 4; nf++) {
        pm[nf] = -3.0e38f;
#pragma unroll
        for (int mf = 0; mf < 4; mf++)
#pragma unroll
            for (int rg = 0; rg < 4; rg++) pm[nf] = fmaxf(pm[nf], e[mf][nf][rg]);
        pm[nf] = fmaxf(pm[nf], __shfl_xor(pm[nf], 16));
        pm[nf] = fmaxf(pm[nf], __shfl_xor(pm[nf], 32));
    }
    if (g == 0) {
#pragma unroll
        for (int nf = 0; nf < 4; nf++) redmax[wj * 128 + wi * 64 + nf * 16 + ln] = pm[nf];
    }
    __syncthreads();
    float fm[4];
#pragma unroll
    for (int nf = 0; nf < 4; nf++) {
        int i = wi * 64 + nf * 16 + ln;
        fm[nf] = fmaxf(redmax[i], redmax[128 + i]);
    }
    float ps[4] = {0.f, 0.f, 0.f, 0.f};
#pragma unroll
    for (int mf = 0; mf < 4; mf++)
#pragma unroll
        for (int nf = 0; nf < 4; nf++)
#pragma unroll
            for (int rg = 0; rg < 4; rg++) {
                float v = __expf(e[mf][nf][rg] - fm[nf]);
                e[mf][nf][rg] = v;
                ps[nf] += v;
            }
#pragma unroll
    for (int nf = 0; nf < 4; nf++) {
        ps[nf] += __shfl_xor(ps[nf], 16);
        ps[nf] += __shfl_xor(ps[nf], 32);
    }
    if (g == 0) {
#pragma unroll
        for (int nf = 0; nf < 4; nf++) redsum[wj * 128 + wi * 64 + nf * 16 + ln] = ps[nf];
    }
    __syncthreads();
    float ivs[4];
#pragma unroll
    for (int nf = 0; nf < 4; nf++) {
        int i = wi * 64 + nf * 16 + ln;
        ivs[nf] = 1.0f / (redsum[i] + redsum[128 + i]);
    }
#pragma unroll
    for (int mf = 0; mf < 4; mf++)
#pragma unroll
        for (int nf = 0; nf < 4; nf++) {
            ushort4 pk;
            pk.x = f2h(e[mf][nf][0] * ivs[nf]);
            pk.y = f2h(e[mf][nf][1] * ivs[nf]);
            pk.z = f2h(e[mf][nf][2] * ivs[nf]);
            pk.w = f2h(e[mf][nf][3] * ivs[nf]);
            *(ushort4*)&Al[(wi * 64 + nf * 16 + ln) * 136 + wj * 64 + mf * 16 + g * 4] = pk;
        }
    __syncthreads();

    int wc = w >> 1, wi2 = w & 1;
    f16x8 bfr[4][4];
#pragma unroll
    for (int nf2 = 0; nf2 < 4; nf2++)
#pragma unroll
        for (int js = 0; js < 4; js++)
            bfr[nf2][js] = *(const f16x8*)&Al[(wi2 * 64 + nf2 * 16 + ln) * 136 + js * 32 + g * 8];

    for (int c0 = 0; c0 < NC; c0 += 64) {
        {
            int cc = tid >> 2, ch = (tid & 3) * 32;
            if (TR == 0) {
                const float* vp = (const float*)vsrc + ((size_t)(b * NC + c0 + cc)) * NHW + (size_t)r * NP + ch;
                u16 tmp[32];
#pragma unroll
                for (int q4 = 0; q4 < 8; q4++) {
                    float4 vv = *(const float4*)(vp + q4 * 4);
                    tmp[q4 * 4 + 0] = f2h(vv.x);
                    tmp[q4 * 4 + 1] = f2h(vv.y);
                    tmp[q4 * 4 + 2] = f2h(vv.z);
                    tmp[q4 * 4 + 3] = f2h(vv.w);
                }
#pragma unroll
                for (int q8 = 0; q8 < 4; q8++)
                    *(uint4*)&Vl[cc * 136 + ch + q8 * 8] = *(uint4*)&tmp[q8 * 8];
            } else {
                const u16* vp = (const u16*)vsrc + ((size_t)(b * NC + c0 + cc)) * NHW + (size_t)r * NP + ch;
#pragma unroll
                for (int q8 = 0; q8 < 4; q8++)
                    *(uint4*)&Vl[cc * 136 + ch + q8 * 8] = *(const uint4*)(vp + q8 * 8);
            }
        }
        __syncthreads();
        f32x4 o[2][4];
#pragma unroll
        for (int mf2 = 0; mf2 < 2; mf2++)
#pragma unroll
            for (int nf2 = 0; nf2 < 4; nf2++) o[mf2][nf2] = 0.0f;
#pragma unroll
        for (int js = 0; js < 4; js++) {
            f16x8 va[2];
#pragma unroll
            for (int mf2 = 0; mf2 < 2; mf2++)
                va[mf2] = *(const f16x8*)&Vl[(wc * 32 + mf2 * 16 + ln) * 136 + js * 32 + g * 8];
#pragma unroll
            for (int mf2 = 0; mf2 < 2; mf2++)
#pragma unroll
                for (int nf2 = 0; nf2 < 4; nf2++)
                    o[mf2][nf2] = __builtin_amdgcn_mfma_f32_16x16x32_f16(va[mf2], bfr[nf2][js], o[mf2][nf2], 0, 0, 0);
        }
#pragma unroll
        for (int mf2 = 0; mf2 < 2; mf2++)
#pragma unroll
            for (int nf2 = 0; nf2 < 4; nf2++)
#pragma unroll
                for (int rg = 0; rg < 4; rg++) {
                    int ci = c0 + wc * 32 + mf2 * 16 + g * 4 + rg;
                    int ii = wi2 * 64 + nf2 * 16 + ln;
                    size_t oa = ((size_t)(b * NC + ci)) * NHW + (size_t)r * NP + ii;
                    if (TR == 0) ((float*)osrc)[oa] = o[mf2][nf2][rg];
                    else         ((u16*)osrc)[oa] = f2h(o[mf2][nf2][rg]);
                }
        __syncthreads();
    }
}

// ---------------- out[plane][h][w] += oht[plane][w][h] (fp16 -> fp32 RMW) ----------------
__global__ __launch_bounds__(256) void addtr_kernel(const u16* __restrict__ oht,
                                                    float* __restrict__ out) {
    __shared__ u16 ts[32][36];
    int plane = blockIdx.y;
    int tile  = blockIdx.x;
    int h0 = (tile >> 2) * 32, w0 = (tile & 3) * 32;
    int r  = threadIdx.x >> 3;
    int c4 = (threadIdx.x & 7) * 4;
    ushort4 v = *(const ushort4*)(oht + (size_t)plane * NHW + (w0 + r) * NP + h0 + c4);
    ts[r][c4 + 0] = v.x; ts[r][c4 + 1] = v.y; ts[r][c4 + 2] = v.z; ts[r][c4 + 3] = v.w;
    __syncthreads();
    float* dst = out + (size_t)plane * NHW + (h0 + r) * NP + w0 + c4;
    float4 cur = *(const float4*)dst;
    cur.x += h2f(ts[c4 + 0][r]);
    cur.y += h2f(ts[c4 + 1][r]);
    cur.z += h2f(ts[c4 + 2][r]);
    cur.w += h2f(ts[c4 + 3][r]);
    *(float4*)dst = cur;
}

extern "C" void kernel_launch(void* const* d_in, const int* in_sizes, int n_in,
                              void* d_out, int out_size, void* d_ws, size_t ws_size,
                              hipStream_t stream) {
    const float* x  = (const float*)d_in[0];
    const float* wq = (const float*)d_in[1];
    const float* bq = (const float*)d_in[2];
    const float* wk = (const float*)d_in[3];
    const float* bk = (const float*)d_in[4];
    float* out = (float*)d_out;

    const size_t QKE = (size_t)NB * NHW * NK;  // 16,777,216 elems
    const size_t XE  = (size_t)NB * NC * NHW;  // 67,108,864 elems
    u16* q   = (u16*)d_ws;
    u16* k   = q + QKE;
    u16* xt  = k + QKE;
    u16* oht = xt + XE;
    u16* wh  = oht + XE;   // 256*512 u16 = 256 KiB

    dim3 blk(256);

    // 0. weights -> fp16
    wconv_kernel<<<dim3(256), blk, 0, stream>>>(wq, wk, wh);
    // 1. x -> xt fp16 transposed [b][c][w][h]
    convtr_kernel<<<dim3(16, NB * NC), blk, 0, stream>>>(x, xt);
    // 2. fused q,k projection (MFMA v2), pixel-major fp16
    proj_kernel<<<dim3(NHW / 128, NB), blk, 0, stream>>>(x, wh, bq, bk, q, k);
    // 3. H-attention -> oht fp16 [b][c][w][h]
    attn_kernel<1><<<dim3(NP, NB), blk, 0, stream>>>(q, k, (const void*)xt, (void*)oht);
    // 4. W-attention -> out fp32 (pure write, overwrites poison)
    attn_kernel<0><<<dim3(NP, NB), blk, 0, stream>>>(q, k, (const void*)x, (void*)out);
    // 5. out += transpose(oht)
    addtr_kernel<<<dim3(16, NB * NC), blk, 0, stream>>>(oht, out);
}

// Round 5
// 543.295 us; speedup vs baseline: 1.4982x; 1.4982x over previous
//
#include <hip/hip_runtime.h>
#include <hip/hip_fp16.h>

#define NB 8
#define NC 512
#define NK 128   // key_dim C2
#define NP 128   // positions per attention row (H = W = 128)
#define NHW 16384

typedef unsigned short u16;
typedef unsigned int u32;
typedef float f32x4 __attribute__((ext_vector_type(4)));
typedef _Float16 f16x8 __attribute__((ext_vector_type(8)));

__device__ __forceinline__ u16 f2h(float f) { return __half_as_ushort(__float2half(f)); }
__device__ __forceinline__ float h2f(u16 u) { return __half2float(__ushort_as_half(u)); }

// ---------------- weights fp32 -> fp16, concatenated [wq;wk] row-major ----------------
__global__ __launch_bounds__(256) void wconv_kernel(const float* __restrict__ wq,
                                                    const float* __restrict__ wk,
                                                    u16* __restrict__ wh) {
    int row = blockIdx.x;  // 0..255
    const float* src = (row < 128) ? (wq + (size_t)row * NC) : (wk + (size_t)(row - 128) * NC);
    int t = threadIdx.x;
    float2 v = *(const float2*)(src + t * 2);
    ushort2 o; o.x = f2h(v.x); o.y = f2h(v.y);
    *(ushort2*)(wh + (size_t)row * NC + t * 2) = o;
}

// ---------------- x fp32 [plane][h][w] -> xt fp16 [plane][w][h] ----------------
__global__ __launch_bounds__(256) void convtr_kernel(const float* __restrict__ x,
                                                     u16* __restrict__ xt) {
    __shared__ u16 ts[32][36];
    int plane = blockIdx.y;
    int tile  = blockIdx.x;
    int h0 = (tile >> 2) * 32, w0 = (tile & 3) * 32;
    const float* ip = x + (size_t)plane * NHW;
    u16* op = xt + (size_t)plane * NHW;
    int r  = threadIdx.x >> 3;
    int c4 = (threadIdx.x & 7) * 4;
    float4 v = *(const float4*)(ip + (h0 + r) * NP + w0 + c4);
    ts[r][c4 + 0] = f2h(v.x); ts[r][c4 + 1] = f2h(v.y);
    ts[r][c4 + 2] = f2h(v.z); ts[r][c4 + 3] = f2h(v.w);
    __syncthreads();
    ushort4 o;
    o.x = ts[c4 + 0][r]; o.y = ts[c4 + 1][r]; o.z = ts[c4 + 2][r]; o.w = ts[c4 + 3][r];
    *(ushort4*)(op + (w0 + r) * NP + h0 + c4) = o;
}

// ---------------- fused q+k projection via MFMA (v2.1) ----------------
// A (x^T tile) staged in LDS double-buffered with XOR swizzle; B (weights fp16)
// read directly from global (L2-resident). Epilogue bounces through LDS for
// coalesced uint4 stores — FULLY UNROLLED so acc indices stay compile-time
// (runtime-indexed ext_vector arrays demote to scratch: 2.3 GB spill traffic in v2).
#define XROW 40   // u16 stride of one p-row in Xt2 (80 B, 16B-aligned)
__device__ __forceinline__ int xt2_off(int p, int cw) {
    // cw = data word index 0..15 (u16 pair); swizzle 4-word blocks by p>>3
    int sw = ((p >> 3) & 3) << 2;
    return p * XROW + 2 * (cw ^ sw);
}

__global__ __launch_bounds__(256) void proj_kernel(const float* __restrict__ x,
                                                   const u16* __restrict__ wh,
                                                   const float* __restrict__ bq,
                                                   const float* __restrict__ bk,
                                                   u16* __restrict__ q,
                                                   u16* __restrict__ k) {
    __shared__ __align__(16) u16 Xt2[2][128 * XROW];
    int b  = blockIdx.y;
    int p0 = blockIdx.x * 128;
    int tid = threadIdx.x;
    int lane = tid & 63, w = tid >> 6;
    int ln = lane & 15, g = lane >> 4;
    int wm = w >> 1, wn = w & 1;

    // per-thread bias for the 8 oc's this thread owns
    float biasv[8];
#pragma unroll
    for (int nf = 0; nf < 8; nf++) {
        int oc = wn * 128 + nf * 16 + ln;
        biasv[nf] = (oc < 128) ? bq[oc] : bk[oc - 128];
    }

    f32x4 acc[4][8];
#pragma unroll
    for (int mf = 0; mf < 4; mf++)
#pragma unroll
        for (int nf = 0; nf < 8; nf++) acc[mf][nf] = 0.0f;

    // staging: thread handles channel rows (c0+2i, c0+2i+1), 8 pixels
    int si  = tid >> 4;          // 0..15
    int spx = (tid & 15) * 8;

#define STAGE(buf, c0)                                                                  \
    {                                                                                   \
        const float* xa = x + ((size_t)(b * NC + (c0) + 2 * si)) * NHW + p0 + spx;      \
        const float* xb = xa + NHW;                                                     \
        float4 a0 = *(const float4*)xa, a1 = *(const float4*)(xa + 4);                  \
        float4 b0 = *(const float4*)xb, b1 = *(const float4*)(xb + 4);                  \
        float av[8] = {a0.x, a0.y, a0.z, a0.w, a1.x, a1.y, a1.z, a1.w};                 \
        float bv[8] = {b0.x, b0.y, b0.z, b0.w, b1.x, b1.y, b1.z, b1.w};                 \
        _Pragma("unroll") for (int j = 0; j < 8; j++) {                                 \
            ushort2 pk;                                                                 \
            pk.x = f2h(av[j]); pk.y = f2h(bv[j]);                                       \
            *(ushort2*)&Xt2[buf][xt2_off(spx + j, si)] = pk;                            \
        }                                                                               \
    }

    STAGE(0, 0);
    __syncthreads();
    for (int t = 0; t < 16; ++t) {
        int c0 = t * 32;
        if (t < 15) STAGE((t + 1) & 1, c0 + 32);
        // B fragments straight from global (L2)
        f16x8 bf[8];
#pragma unroll
        for (int nf = 0; nf < 8; nf++)
            bf[nf] = *(const f16x8*)&wh[((size_t)(wn * 128 + nf * 16 + ln)) * NC + c0 + g * 8];
        // A fragments from LDS (swizzled)
        f16x8 af[4];
#pragma unroll
        for (int mf = 0; mf < 4; mf++)
            af[mf] = *(const f16x8*)&Xt2[t & 1][xt2_off(wm * 64 + mf * 16 + ln, g * 4)];
#pragma unroll
        for (int mf = 0; mf < 4; mf++)
#pragma unroll
            for (int nf = 0; nf < 8; nf++)
                acc[mf][nf] = __builtin_amdgcn_mfma_f32_16x16x32_f16(af[mf], bf[nf], acc[mf][nf], 0, 0, 0);
        __syncthreads();
    }
#undef STAGE

    // ---- epilogue: LDS bounce for coalesced stores (FULLY unrolled) ----
    u16* Ep = &Xt2[0][0];      // 128 rows x 72 u16 = 9216 u16 (fits in 10240)
#pragma unroll
    for (int oh = 0; oh < 4; oh++) {
        const int wn_sel = oh >> 1;
        const int nf0 = (oh & 1) * 4;
        if (wn == wn_sel) {
#pragma unroll
            for (int mf = 0; mf < 4; mf++)
#pragma unroll
                for (int nfi = 0; nfi < 4; nfi++) {
                    const int nf = nf0 + nfi;
#pragma unroll
                    for (int rg = 0; rg < 4; rg++) {
                        int prow = wm * 64 + mf * 16 + g * 4 + rg;
                        Ep[prow * 72 + nfi * 16 + ln] = f2h(acc[mf][nf][rg] + biasv[nf]);
                    }
                }
        }
        __syncthreads();
        {
            int p = tid >> 1, half = tid & 1;
            u16* dst = (oh < 2 ? q : k) + ((size_t)(b * NHW + p0 + p)) * NK + (oh & 1) * 64 + half * 32;
            const u16* srcl = &Ep[p * 72 + half * 32];
#pragma unroll
            for (int e = 0; e < 4; e++)
                *(uint4*)(dst + e * 8) = *(const uint4*)(srcl + e * 8);
        }
        __syncthreads();
    }
}

// ---------------- axis attention via MFMA ----------------
// TR=0 (W-pass): r=h, Q/K rows contiguous, V = x fp32, out = float*
// TR=1 (H-pass): r=w, Q/K rows strided, V = xt fp16, out = oht fp16
template <int TR>
__global__ __launch_bounds__(256) void attn_kernel(const u16* __restrict__ q,
                                                   const u16* __restrict__ k,
                                                   const void* __restrict__ vsrc,
                                                   void* __restrict__ osrc) {
    __shared__ __align__(16) u16 smem[2 * 128 * 136];
    __shared__ float redmax[256];
    __shared__ float redsum[256];
    u16* Ks = smem;
    u16* Qs = smem + 128 * 136;
    u16* Al = smem;
    u16* Vl = smem + 128 * 136;

    int r = blockIdx.x, b = blockIdx.y;
    int tid = threadIdx.x;
    int lane = tid & 63, w = tid >> 6;
    int ln = lane & 15, g = lane >> 4;

    const size_t base = TR ? ((size_t)b * NHW + r) * NK : ((size_t)b * NHW + (size_t)r * NP) * NK;
    const int qrs = TR ? NP * NK : NK;

    {
        int j = tid >> 1, hf = tid & 1;
        const u16* qp2 = q + base + (size_t)j * qrs + hf * 64;
        const u16* kp2 = k + base + (size_t)j * qrs + hf * 64;
#pragma unroll
        for (int e = 0; e < 8; e++) {
            *(uint4*)&Qs[j * 136 + hf * 64 + e * 8] = *(const uint4*)(qp2 + e * 8);
            *(uint4*)&Ks[j * 136 + hf * 64 + e * 8] = *(const uint4*)(kp2 + e * 8);
        }
    }
    __syncthreads();

    int wj = w >> 1, wi = w & 1;
    f32x4 e[4][4];
#pragma unroll
    for (int mf = 0; mf < 4; mf++)
#pragma unroll
        for (int nf = 0; nf < 4; nf++) e[mf][nf] = 0.0f;
#pragma unroll
    for (int ks = 0; ks < 4; ks++) {
        f16x8 qa[4], kb[4];
#pragma unroll
        for (int mf = 0; mf < 4; mf++)
            qa[mf] = *(const f16x8*)&Qs[(wj * 64 + mf * 16 + ln) * 136 + ks * 32 + g * 8];
#pragma unroll
        for (int nf = 0; nf < 4; nf++)
            kb[nf] = *(const f16x8*)&Ks[(wi * 64 + nf * 16 + ln) * 136 + ks * 32 + g * 8];
#pragma unroll
        for (int mf = 0; mf < 4; mf++)
#pragma unroll
            for (int nf = 0; nf < 4; nf++)
                e[mf][nf] = __builtin_amdgcn_mfma_f32_16x16x32_f16(qa[mf], kb[nf], e[mf][nf], 0, 0, 0);
    }

    float pm[4];
#pragma unroll
    for (int nf = 0; nf < 4; nf++) {
        pm[nf] = -3.0e38f;
#pragma unroll
        for (int mf = 0; mf < 4; mf++)
#pragma unroll
            for (int rg = 0; rg < 4; rg++) pm[nf] = fmaxf(pm[nf], e[mf][nf][rg]);
        pm[nf] = fmaxf(pm[nf], __shfl_xor(pm[nf], 16));
        pm[nf] = fmaxf(pm[nf], __shfl_xor(pm[nf], 32));
    }
    if (g == 0) {
#pragma unroll
        for (int nf = 0; nf < 4; nf++) redmax[wj * 128 + wi * 64 + nf * 16 + ln] = pm[nf];
    }
    __syncthreads();
    float fm[4];
#pragma unroll
    for (int nf = 0; nf < 4; nf++) {
        int i = wi * 64 + nf * 16 + ln;
        fm[nf] = fmaxf(redmax[i], redmax[128 + i]);
    }
    float ps[4] = {0.f, 0.f, 0.f, 0.f};
#pragma unroll
    for (int mf = 0; mf < 4; mf++)
#pragma unroll
        for (int nf = 0; nf < 4; nf++)
#pragma unroll
            for (int rg = 0; rg < 4; rg++) {
                float v = __expf(e[mf][nf][rg] - fm[nf]);
                e[mf][nf][rg] = v;
                ps[nf] += v;
            }
#pragma unroll
    for (int nf = 0; nf < 4; nf++) {
        ps[nf] += __shfl_xor(ps[nf], 16);
        ps[nf] += __shfl_xor(ps[nf], 32);
    }
    if (g == 0) {
#pragma unroll
        for (int nf = 0; nf < 4; nf++) redsum[wj * 128 + wi * 64 + nf * 16 + ln] = ps[nf];
    }
    __syncthreads();
    float ivs[4];
#pragma unroll
    for (int nf = 0; nf < 4; nf++) {
        int i = wi * 64 + nf * 16 + ln;
        ivs[nf] = 1.0f / (redsum[i] + redsum[128 + i]);
    }
#pragma unroll
    for (int mf = 0; mf < 4; mf++)
#pragma unroll
        for (int nf = 0; nf < 4; nf++) {
            ushort4 pk;
            pk.x = f2h(e[mf][nf][0] * ivs[nf]);
            pk.y = f2h(e[mf][nf][1] * ivs[nf]);
            pk.z = f2h(e[mf][nf][2] * ivs[nf]);
            pk.w = f2h(e[mf][nf][3] * ivs[nf]);
            *(ushort4*)&Al[(wi * 64 + nf * 16 + ln) * 136 + wj * 64 + mf * 16 + g * 4] = pk;
        }
    __syncthreads();

    int wc = w >> 1, wi2 = w & 1;
    f16x8 bfr[4][4];
#pragma unroll
    for (int nf2 = 0; nf2 < 4; nf2++)
#pragma unroll
        for (int js = 0; js < 4; js++)
            bfr[nf2][js] = *(const f16x8*)&Al[(wi2 * 64 + nf2 * 16 + ln) * 136 + js * 32 + g * 8];

    for (int c0 = 0; c0 < NC; c0 += 64) {
        {
            int cc = tid >> 2, ch = (tid & 3) * 32;
            if (TR == 0) {
                const float* vp = (const float*)vsrc + ((size_t)(b * NC + c0 + cc)) * NHW + (size_t)r * NP + ch;
                u16 tmp[32];
#pragma unroll
                for (int q4 = 0; q4 < 8; q4++) {
                    float4 vv = *(const float4*)(vp + q4 * 4);
                    tmp[q4 * 4 + 0] = f2h(vv.x);
                    tmp[q4 * 4 + 1] = f2h(vv.y);
                    tmp[q4 * 4 + 2] = f2h(vv.z);
                    tmp[q4 * 4 + 3] = f2h(vv.w);
                }
#pragma unroll
                for (int q8 = 0; q8 < 4; q8++)
                    *(uint4*)&Vl[cc * 136 + ch + q8 * 8] = *(uint4*)&tmp[q8 * 8];
            } else {
                const u16* vp = (const u16*)vsrc + ((size_t)(b * NC + c0 + cc)) * NHW + (size_t)r * NP + ch;
#pragma unroll
                for (int q8 = 0; q8 < 4; q8++)
                    *(uint4*)&Vl[cc * 136 + ch + q8 * 8] = *(const uint4*)(vp + q8 * 8);
            }
        }
        __syncthreads();
        f32x4 o[2][4];
#pragma unroll
        for (int mf2 = 0; mf2 < 2; mf2++)
#pragma unroll
            for (int nf2 = 0; nf2 < 4; nf2++) o[mf2][nf2] = 0.0f;
#pragma unroll
        for (int js = 0; js < 4; js++) {
            f16x8 va[2];
#pragma unroll
            for (int mf2 = 0; mf2 < 2; mf2++)
                va[mf2] = *(const f16x8*)&Vl[(wc * 32 + mf2 * 16 + ln) * 136 + js * 32 + g * 8];
#pragma unroll
            for (int mf2 = 0; mf2 < 2; mf2++)
#pragma unroll
                for (int nf2 = 0; nf2 < 4; nf2++)
                    o[mf2][nf2] = __builtin_amdgcn_mfma_f32_16x16x32_f16(va[mf2], bfr[nf2][js], o[mf2][nf2], 0, 0, 0);
        }
#pragma unroll
        for (int mf2 = 0; mf2 < 2; mf2++)
#pragma unroll
            for (int nf2 = 0; nf2 < 4; nf2++)
#pragma unroll
                for (int rg = 0; rg < 4; rg++) {
                    int ci = c0 + wc * 32 + mf2 * 16 + g * 4 + rg;
                    int ii = wi2 * 64 + nf2 * 16 + ln;
                    size_t oa = ((size_t)(b * NC + ci)) * NHW + (size_t)r * NP + ii;
                    if (TR == 0) ((float*)osrc)[oa] = o[mf2][nf2][rg];
                    else         ((u16*)osrc)[oa] = f2h(o[mf2][nf2][rg]);
                }
        __syncthreads();
    }
}

// ---------------- out[plane][h][w] += oht[plane][w][h] (fp16 -> fp32 RMW) ----------------
__global__ __launch_bounds__(256) void addtr_kernel(const u16* __restrict__ oht,
                                                    float* __restrict__ out) {
    __shared__ u16 ts[32][36];
    int plane = blockIdx.y;
    int tile  = blockIdx.x;
    int h0 = (tile >> 2) * 32, w0 = (tile & 3) * 32;
    int r  = threadIdx.x >> 3;
    int c4 = (threadIdx.x & 7) * 4;
    ushort4 v = *(const ushort4*)(oht + (size_t)plane * NHW + (w0 + r) * NP + h0 + c4);
    ts[r][c4 + 0] = v.x; ts[r][c4 + 1] = v.y; ts[r][c4 + 2] = v.z; ts[r][c4 + 3] = v.w;
    __syncthreads();
    float* dst = out + (size_t)plane * NHW + (h0 + r) * NP + w0 + c4;
    float4 cur = *(const float4*)dst;
    cur.x += h2f(ts[c4 + 0][r]);
    cur.y += h2f(ts[c4 + 1][r]);
    cur.z += h2f(ts[c4 + 2][r]);
    cur.w += h2f(ts[c4 + 3][r]);
    *(float4*)dst = cur;
}

extern "C" void kernel_launch(void* const* d_in, const int* in_sizes, int n_in,
                              void* d_out, int out_size, void* d_ws, size_t ws_size,
                              hipStream_t stream) {
    const float* x  = (const float*)d_in[0];
    const float* wq = (const float*)d_in[1];
    const float* bq = (const float*)d_in[2];
    const float* wk = (const float*)d_in[3];
    const float* bk = (const float*)d_in[4];
    float* out = (float*)d_out;

    const size_t QKE = (size_t)NB * NHW * NK;  // 16,777,216 elems
    const size_t XE  = (size_t)NB * NC * NHW;  // 67,108,864 elems
    u16* q   = (u16*)d_ws;
    u16* k   = q + QKE;
    u16* xt  = k + QKE;
    u16* oht = xt + XE;
    u16* wh  = oht + XE;   // 256*512 u16 = 256 KiB

    dim3 blk(256);

    // 0. weights -> fp16
    wconv_kernel<<<dim3(256), blk, 0, stream>>>(wq, wk, wh);
    // 1. x -> xt fp16 transposed [b][c][w][h]
    convtr_kernel<<<dim3(16, NB * NC), blk, 0, stream>>>(x, xt);
    // 2. fused q,k projection (MFMA v2.1), pixel-major fp16
    proj_kernel<<<dim3(NHW / 128, NB), blk, 0, stream>>>(x, wh, bq, bk, q, k);
    // 3. H-attention -> oht fp16 [b][c][w][h]
    attn_kernel<1><<<dim3(NP, NB), blk, 0, stream>>>(q, k, (const void*)xt, (void*)oht);
    // 4. W-attention -> out fp32 (pure write, overwrites poison)
    attn_kernel<0><<<dim3(NP, NB), blk, 0, stream>>>(q, k, (const void*)x, (void*)out);
    // 5. out += transpose(oht)
    addtr_kernel<<<dim3(16, NB * NC), blk, 0, stream>>>(oht, out);
}

// Round 7
// 505.216 us; speedup vs baseline: 1.6111x; 1.0754x over previous
//
#include <hip/hip_runtime.h>
#include <hip/hip_fp16.h>

#define NB 8
#define NC 512
#define NK 128   // key_dim C2
#define NP 128   // positions per attention row (H = W = 128)
#define NHW 16384

typedef unsigned short u16;
typedef unsigned int u32;
typedef float f32x4 __attribute__((ext_vector_type(4)));
typedef _Float16 f16x8 __attribute__((ext_vector_type(8)));

__device__ __forceinline__ u16 f2h(float f) { return __half_as_ushort(__float2half(f)); }
__device__ __forceinline__ float h2f(u16 u) { return __half2float(__ushort_as_half(u)); }

// ---------------- weights fp32 -> fp16, concatenated [wq;wk] row-major ----------------
__global__ __launch_bounds__(256) void wconv_kernel(const float* __restrict__ wq,
                                                    const float* __restrict__ wk,
                                                    u16* __restrict__ wh) {
    int row = blockIdx.x;  // 0..255
    const float* src = (row < 128) ? (wq + (size_t)row * NC) : (wk + (size_t)(row - 128) * NC);
    int t = threadIdx.x;
    float2 v = *(const float2*)(src + t * 2);
    ushort2 o; o.x = f2h(v.x); o.y = f2h(v.y);
    *(ushort2*)(wh + (size_t)row * NC + t * 2) = o;
}

// ---------------- x fp32 [plane][h][w] -> xt fp16 [plane][w][h] ----------------
__global__ __launch_bounds__(256) void convtr_kernel(const float* __restrict__ x,
                                                     u16* __restrict__ xt) {
    __shared__ u16 ts[32][36];
    int plane = blockIdx.y;
    int tile  = blockIdx.x;
    int h0 = (tile >> 2) * 32, w0 = (tile & 3) * 32;
    const float* ip = x + (size_t)plane * NHW;
    u16* op = xt + (size_t)plane * NHW;
    int r  = threadIdx.x >> 3;
    int c4 = (threadIdx.x & 7) * 4;
    float4 v = *(const float4*)(ip + (h0 + r) * NP + w0 + c4);
    ts[r][c4 + 0] = f2h(v.x); ts[r][c4 + 1] = f2h(v.y);
    ts[r][c4 + 2] = f2h(v.z); ts[r][c4 + 3] = f2h(v.w);
    __syncthreads();
    ushort4 o;
    o.x = ts[c4 + 0][r]; o.y = ts[c4 + 1][r]; o.z = ts[c4 + 2][r]; o.w = ts[c4 + 3][r];
    *(ushort4*)(op + (w0 + r) * NP + h0 + c4) = o;
}

// ---------------- fused q+k projection via MFMA (v3) ----------------
// Block tile: 64 px x 256 oc. Wave w owns 64 px x 64 oc (acc[4][4] = 64 regs,
// keeping total regs <= ~170 so 3 waves/SIMD fit — v2.1's acc[4][8]=128 AGPRs
// pushed the unified file past 256 -> 1 wave/SIMD, pure latency exposure).
// A (x^T tile) double-buffered in LDS (XOR swizzle); B (fp16 weights) straight
// from global/L2. Epilogue: LDS bounce, q then k, fully unrolled.
#define XROW 40   // u16 stride of one p-row (80 B, 16B-aligned)
__device__ __forceinline__ int xt2_off(int p, int cw) {
    int sw = ((p >> 3) & 3) << 2;
    return p * XROW + 2 * (cw ^ sw);
}

__global__ __launch_bounds__(256, 3) void proj_kernel(const float* __restrict__ x,
                                                      const u16* __restrict__ wh,
                                                      const float* __restrict__ bq,
                                                      const float* __restrict__ bk,
                                                      u16* __restrict__ q,
                                                      u16* __restrict__ k) {
    // staging: 2 x (64 x XROW) = 5120 u16; epilogue bounce: 64 x 136 = 8704 u16
    __shared__ __align__(16) u16 smem[9216];
    int b  = blockIdx.y;
    int p0 = blockIdx.x * 64;
    int tid = threadIdx.x;
    int lane = tid & 63, w = tid >> 6;
    int ln = lane & 15, g = lane >> 4;

    // wave w owns oc quadrant [w*64, w*64+64)
    float biasv[4];
#pragma unroll
    for (int nf = 0; nf < 4; nf++) {
        int oc = w * 64 + nf * 16 + ln;
        biasv[nf] = (oc < 128) ? bq[oc] : bk[oc - 128];
    }

    f32x4 acc[4][4];
#pragma unroll
    for (int mf = 0; mf < 4; mf++)
#pragma unroll
        for (int nf = 0; nf < 4; nf++) acc[mf][nf] = 0.0f;

    // staging: thread handles channel pair (c0+2si, c0+2si+1), 4 pixels
    int si  = tid >> 4;          // 0..15
    int spx = (tid & 15) * 4;

#define STAGE(buf, c0)                                                                  \
    {                                                                                   \
        const float* xa = x + ((size_t)(b * NC + (c0) + 2 * si)) * NHW + p0 + spx;      \
        const float* xb = xa + NHW;                                                     \
        float4 a0 = *(const float4*)xa;                                                 \
        float4 b0 = *(const float4*)xb;                                                 \
        float av[4] = {a0.x, a0.y, a0.z, a0.w};                                         \
        float bv[4] = {b0.x, b0.y, b0.z, b0.w};                                         \
        _Pragma("unroll") for (int j = 0; j < 4; j++) {                                 \
            ushort2 pk;                                                                 \
            pk.x = f2h(av[j]); pk.y = f2h(bv[j]);                                       \
            *(ushort2*)&smem[(buf) * 2560 + xt2_off(spx + j, si)] = pk;                 \
        }                                                                               \
    }

    STAGE(0, 0);
    __syncthreads();
    for (int t = 0; t < 16; ++t) {
        int c0 = t * 32;
        if (t < 15) STAGE((t + 1) & 1, c0 + 32);
        f16x8 bf[4];
#pragma unroll
        for (int nf = 0; nf < 4; nf++)
            bf[nf] = *(const f16x8*)&wh[((size_t)(w * 64 + nf * 16 + ln)) * NC + c0 + g * 8];
        f16x8 af[4];
#pragma unroll
        for (int mf = 0; mf < 4; mf++)
            af[mf] = *(const f16x8*)&smem[(t & 1) * 2560 + xt2_off(mf * 16 + ln, g * 4)];
#pragma unroll
        for (int mf = 0; mf < 4; mf++)
#pragma unroll
            for (int nf = 0; nf < 4; nf++)
                acc[mf][nf] = __builtin_amdgcn_mfma_f32_16x16x32_f16(af[mf], bf[nf], acc[mf][nf], 0, 0, 0);
        __syncthreads();
    }
#undef STAGE

    // ---- epilogue: LDS bounce, pass 0 = q (waves 0,1), pass 1 = k (waves 2,3) ----
#pragma unroll
    for (int pass = 0; pass < 2; pass++) {
        if ((w >> 1) == pass) {
            int colbase = (w & 1) * 64;
#pragma unroll
            for (int mf = 0; mf < 4; mf++)
#pragma unroll
                for (int nf = 0; nf < 4; nf++)
#pragma unroll
                    for (int rg = 0; rg < 4; rg++) {
                        int p = mf * 16 + g * 4 + rg;
                        smem[p * 136 + colbase + nf * 16 + ln] = f2h(acc[mf][nf][rg] + biasv[nf]);
                    }
        }
        __syncthreads();
        {
            int p = tid >> 2, seg = tid & 3;
            u16* dst = (pass == 0 ? q : k) + ((size_t)(b * NHW + p0 + p)) * NK + seg * 32;
            const u16* srcl = &smem[p * 136 + seg * 32];
            *(uint4*)(dst)     = *(const uint4*)(srcl);
            *(uint4*)(dst + 8) = *(const uint4*)(srcl + 8);
            *(uint4*)(dst + 16) = *(const uint4*)(srcl + 16);
            *(uint4*)(dst + 24) = *(const uint4*)(srcl + 24);
        }
        __syncthreads();
    }
}

// ---------------- axis attention via MFMA ----------------
// TR=0 (W-pass): r=h, Q/K rows contiguous, V = x fp32, out = float*
// TR=1 (H-pass): r=w, Q/K rows strided, V = xt fp16, out = oht fp16
template <int TR>
__global__ __launch_bounds__(256) void attn_kernel(const u16* __restrict__ q,
                                                   const u16* __restrict__ k,
                                                   const void* __restrict__ vsrc,
                                                   void* __restrict__ osrc) {
    __shared__ __align__(16) u16 smem[2 * 128 * 136];
    __shared__ float redmax[256];
    __shared__ float redsum[256];
    u16* Ks = smem;
    u16* Qs = smem + 128 * 136;
    u16* Al = smem;
    u16* Vl = smem + 128 * 136;

    int r = blockIdx.x, b = blockIdx.y;
    int tid = threadIdx.x;
    int lane = tid & 63, w = tid >> 6;
    int ln = lane & 15, g = lane >> 4;

    const size_t base = TR ? ((size_t)b * NHW + r) * NK : ((size_t)b * NHW + (size_t)r * NP) * NK;
    const int qrs = TR ? NP * NK : NK;

    {
        int j = tid >> 1, hf = tid & 1;
        const u16* qp2 = q + base + (size_t)j * qrs + hf * 64;
        const u16* kp2 = k + base + (size_t)j * qrs + hf * 64;
#pragma unroll
        for (int e = 0; e < 8; e++) {
            *(uint4*)&Qs[j * 136 + hf * 64 + e * 8] = *(const uint4*)(qp2 + e * 8);
            *(uint4*)&Ks[j * 136 + hf * 64 + e * 8] = *(const uint4*)(kp2 + e * 8);
        }
    }
    __syncthreads();

    int wj = w >> 1, wi = w & 1;
    f32x4 e[4][4];
#pragma unroll
    for (int mf = 0; mf < 4; mf++)
#pragma unroll
        for (int nf = 0; nf < 4; nf++) e[mf][nf] = 0.0f;
#pragma unroll
    for (int ks = 0; ks < 4; ks++) {
        f16x8 qa[4], kb[4];
#pragma unroll
        for (int mf = 0; mf < 4; mf++)
            qa[mf] = *(const f16x8*)&Qs[(wj * 64 + mf * 16 + ln) * 136 + ks * 32 + g * 8];
#pragma unroll
        for (int nf = 0; nf < 4; nf++)
            kb[nf] = *(const f16x8*)&Ks[(wi * 64 + nf * 16 + ln) * 136 + ks * 32 + g * 8];
#pragma unroll
        for (int mf = 0; mf < 4; mf++)
#pragma unroll
            for (int nf = 0; nf < 4; nf++)
                e[mf][nf] = __builtin_amdgcn_mfma_f32_16x16x32_f16(qa[mf], kb[nf], e[mf][nf], 0, 0, 0);
    }

    float pm[4];
#pragma unroll
    for (int nf = 0; nf < 4; nf++) {
        pm[nf] = -3.0e38f;
#pragma unroll
        for (int mf = 0; mf < 4; mf++)
#pragma unroll
            for (int rg = 0; rg < 4; rg++) pm[nf] = fmaxf(pm[nf], e[mf][nf][rg]);
        pm[nf] = fmaxf(pm[nf], __shfl_xor(pm[nf], 16));
        pm[nf] = fmaxf(pm[nf], __shfl_xor(pm[nf], 32));
    }
    if (g == 0) {
#pragma unroll
        for (int nf = 0; nf < 4; nf++) redmax[wj * 128 + wi * 64 + nf * 16 + ln] = pm[nf];
    }
    __syncthreads();
    float fm[4];
#pragma unroll
    for (int nf = 0; nf < 4; nf++) {
        int i = wi * 64 + nf * 16 + ln;
        fm[nf] = fmaxf(redmax[i], redmax[128 + i]);
    }
    float ps[4] = {0.f, 0.f, 0.f, 0.f};
#pragma unroll
    for (int mf = 0; mf < 4; mf++)
#pragma unroll
        for (int nf = 0; nf < 4; nf++)
#pragma unroll
            for (int rg = 0; rg < 4; rg++) {
                float v = __expf(e[mf][nf][rg] - fm[nf]);
                e[mf][nf][rg] = v;
                ps[nf] += v;
            }
#pragma unroll
    for (int nf = 0; nf < 4; nf++) {
        ps[nf] += __shfl_xor(ps[nf], 16);
        ps[nf] += __shfl_xor(ps[nf], 32);
    }
    if (g == 0) {
#pragma unroll
        for (int nf = 0; nf < 4; nf++) redsum[wj * 128 + wi * 64 + nf * 16 + ln] = ps[nf];
    }
    __syncthreads();
    float ivs[4];
#pragma unroll
    for (int nf = 0; nf < 4; nf++) {
        int i = wi * 64 + nf * 16 + ln;
        ivs[nf] = 1.0f / (redsum[i] + redsum[128 + i]);
    }
#pragma unroll
    for (int mf = 0; mf < 4; mf++)
#pragma unroll
        for (int nf = 0; nf < 4; nf++) {
            ushort4 pk;
            pk.x = f2h(e[mf][nf][0] * ivs[nf]);
            pk.y = f2h(e[mf][nf][1] * ivs[nf]);
            pk.z = f2h(e[mf][nf][2] * ivs[nf]);
            pk.w = f2h(e[mf][nf][3] * ivs[nf]);
            *(ushort4*)&Al[(wi * 64 + nf * 16 + ln) * 136 + wj * 64 + mf * 16 + g * 4] = pk;
        }
    __syncthreads();

    int wc = w >> 1, wi2 = w & 1;
    f16x8 bfr[4][4];
#pragma unroll
    for (int nf2 = 0; nf2 < 4; nf2++)
#pragma unroll
        for (int js = 0; js < 4; js++)
            bfr[nf2][js] = *(const f16x8*)&Al[(wi2 * 64 + nf2 * 16 + ln) * 136 + js * 32 + g * 8];

    for (int c0 = 0; c0 < NC; c0 += 64) {
        {
            int cc = tid >> 2, ch = (tid & 3) * 32;
            if (TR == 0) {
                const float* vp = (const float*)vsrc + ((size_t)(b * NC + c0 + cc)) * NHW + (size_t)r * NP + ch;
                u16 tmp[32];
#pragma unroll
                for (int q4 = 0; q4 < 8; q4++) {
                    float4 vv = *(const float4*)(vp + q4 * 4);
                    tmp[q4 * 4 + 0] = f2h(vv.x);
                    tmp[q4 * 4 + 1] = f2h(vv.y);
                    tmp[q4 * 4 + 2] = f2h(vv.z);
                    tmp[q4 * 4 + 3] = f2h(vv.w);
                }
#pragma unroll
                for (int q8 = 0; q8 < 4; q8++)
                    *(uint4*)&Vl[cc * 136 + ch + q8 * 8] = *(uint4*)&tmp[q8 * 8];
            } else {
                const u16* vp = (const u16*)vsrc + ((size_t)(b * NC + c0 + cc)) * NHW + (size_t)r * NP + ch;
#pragma unroll
                for (int q8 = 0; q8 < 4; q8++)
                    *(uint4*)&Vl[cc * 136 + ch + q8 * 8] = *(const uint4*)(vp + q8 * 8);
            }
        }
        __syncthreads();
        f32x4 o[2][4];
#pragma unroll
        for (int mf2 = 0; mf2 < 2; mf2++)
#pragma unroll
            for (int nf2 = 0; nf2 < 4; nf2++) o[mf2][nf2] = 0.0f;
#pragma unroll
        for (int js = 0; js < 4; js++) {
            f16x8 va[2];
#pragma unroll
            for (int mf2 = 0; mf2 < 2; mf2++)
                va[mf2] = *(const f16x8*)&Vl[(wc * 32 + mf2 * 16 + ln) * 136 + js * 32 + g * 8];
#pragma unroll
            for (int mf2 = 0; mf2 < 2; mf2++)
#pragma unroll
                for (int nf2 = 0; nf2 < 4; nf2++)
                    o[mf2][nf2] = __builtin_amdgcn_mfma_f32_16x16x32_f16(va[mf2], bfr[nf2][js], o[mf2][nf2], 0, 0, 0);
        }
#pragma unroll
        for (int mf2 = 0; mf2 < 2; mf2++)
#pragma unroll
            for (int nf2 = 0; nf2 < 4; nf2++)
#pragma unroll
                for (int rg = 0; rg < 4; rg++) {
                    int ci = c0 + wc * 32 + mf2 * 16 + g * 4 + rg;
                    int ii = wi2 * 64 + nf2 * 16 + ln;
                    size_t oa = ((size_t)(b * NC + ci)) * NHW + (size_t)r * NP + ii;
                    if (TR == 0) ((float*)osrc)[oa] = o[mf2][nf2][rg];
                    else         ((u16*)osrc)[oa] = f2h(o[mf2][nf2][rg]);
                }
        __syncthreads();
    }
}

// ---------------- out[plane][h][w] += oht[plane][w][h] (fp16 -> fp32 RMW) ----------------
__global__ __launch_bounds__(256) void addtr_kernel(const u16* __restrict__ oht,
                                                    float* __restrict__ out) {
    __shared__ u16 ts[32][36];
    int plane = blockIdx.y;
    int tile  = blockIdx.x;
    int h0 = (tile >> 2) * 32, w0 = (tile & 3) * 32;
    int r  = threadIdx.x >> 3;
    int c4 = (threadIdx.x & 7) * 4;
    ushort4 v = *(const ushort4*)(oht + (size_t)plane * NHW + (w0 + r) * NP + h0 + c4);
    ts[r][c4 + 0] = v.x; ts[r][c4 + 1] = v.y; ts[r][c4 + 2] = v.z; ts[r][c4 + 3] = v.w;
    __syncthreads();
    float* dst = out + (size_t)plane * NHW + (h0 + r) * NP + w0 + c4;
    float4 cur = *(const float4*)dst;
    cur.x += h2f(ts[c4 + 0][r]);
    cur.y += h2f(ts[c4 + 1][r]);
    cur.z += h2f(ts[c4 + 2][r]);
    cur.w += h2f(ts[c4 + 3][r]);
    *(float4*)dst = cur;
}

extern "C" void kernel_launch(void* const* d_in, const int* in_sizes, int n_in,
                              void* d_out, int out_size, void* d_ws, size_t ws_size,
                              hipStream_t stream) {
    const float* x  = (const float*)d_in[0];
    const float* wq = (const float*)d_in[1];
    const float* bq = (const float*)d_in[2];
    const float* wk = (const float*)d_in[3];
    const float* bk = (const float*)d_in[4];
    float* out = (float*)d_out;

    const size_t QKE = (size_t)NB * NHW * NK;  // 16,777,216 elems
    const size_t XE  = (size_t)NB * NC * NHW;  // 67,108,864 elems
    u16* q   = (u16*)d_ws;
    u16* k   = q + QKE;
    u16* xt  = k + QKE;
    u16* oht = xt + XE;
    u16* wh  = oht + XE;   // 256*512 u16 = 256 KiB

    dim3 blk(256);

    // 0. weights -> fp16
    wconv_kernel<<<dim3(256), blk, 0, stream>>>(wq, wk, wh);
    // 1. x -> xt fp16 transposed [b][c][w][h]
    convtr_kernel<<<dim3(16, NB * NC), blk, 0, stream>>>(x, xt);
    // 2. fused q,k projection (MFMA v3, 64px x 256oc tiles), pixel-major fp16
    proj_kernel<<<dim3(NHW / 64, NB), blk, 0, stream>>>(x, wh, bq, bk, q, k);
    // 3. H-attention -> oht fp16 [b][c][w][h]
    attn_kernel<1><<<dim3(NP, NB), blk, 0, stream>>>(q, k, (const void*)xt, (void*)oht);
    // 4. W-attention -> out fp32 (pure write, overwrites poison)
    attn_kernel<0><<<dim3(NP, NB), blk, 0, stream>>>(q, k, (const void*)x, (void*)out);
    // 5. out += transpose(oht)
    addtr_kernel<<<dim3(16, NB * NC), blk, 0, stream>>>(oht, out);
}

// Round 10
// 494.777 us; speedup vs baseline: 1.6451x; 1.0211x over previous
//
#include <hip/hip_runtime.h>
#include <hip/hip_fp16.h>

#define NB 8
#define NC 512
#define NK 128   // key_dim C2
#define NP 128   // positions per attention row (H = W = 128)
#define NHW 16384

typedef unsigned short u16;
typedef unsigned int u32;
typedef float f32x4 __attribute__((ext_vector_type(4)));
typedef _Float16 f16x8 __attribute__((ext_vector_type(8)));

__device__ __forceinline__ u16 f2h(float f) { return __half_as_ushort(__float2half(f)); }
__device__ __forceinline__ float h2f(u16 u) { return __half2float(__ushort_as_half(u)); }

// ---------------- weights fp32 -> fp16, concatenated [wq;wk] row-major ----------------
__global__ __launch_bounds__(256) void wconv_kernel(const float* __restrict__ wq,
                                                    const float* __restrict__ wk,
                                                    u16* __restrict__ wh) {
    int row = blockIdx.x;  // 0..255
    const float* src = (row < 128) ? (wq + (size_t)row * NC) : (wk + (size_t)(row - 128) * NC);
    int t = threadIdx.x;
    float2 v = *(const float2*)(src + t * 2);
    ushort2 o; o.x = f2h(v.x); o.y = f2h(v.y);
    *(ushort2*)(wh + (size_t)row * NC + t * 2) = o;
}

// ---------------- x fp32 [plane][h][w] -> xt fp16 [plane][w][h] ----------------
__global__ __launch_bounds__(256) void convtr_kernel(const float* __restrict__ x,
                                                     u16* __restrict__ xt) {
    __shared__ u16 ts[32][36];
    int plane = blockIdx.y;
    int tile  = blockIdx.x;
    int h0 = (tile >> 2) * 32, w0 = (tile & 3) * 32;
    const float* ip = x + (size_t)plane * NHW;
    u16* op = xt + (size_t)plane * NHW;
    int r  = threadIdx.x >> 3;
    int c4 = (threadIdx.x & 7) * 4;
    float4 v = *(const float4*)(ip + (h0 + r) * NP + w0 + c4);
    ts[r][c4 + 0] = f2h(v.x); ts[r][c4 + 1] = f2h(v.y);
    ts[r][c4 + 2] = f2h(v.z); ts[r][c4 + 3] = f2h(v.w);
    __syncthreads();
    ushort4 o;
    o.x = ts[c4 + 0][r]; o.y = ts[c4 + 1][r]; o.z = ts[c4 + 2][r]; o.w = ts[c4 + 3][r];
    *(ushort4*)(op + (w0 + r) * NP + h0 + c4) = o;
}

// ---------------- fused q+k projection via MFMA (v3, unchanged) ----------------
#define XROW 40   // u16 stride of one p-row (80 B, 16B-aligned)
__device__ __forceinline__ int xt2_off(int p, int cw) {
    int sw = ((p >> 3) & 3) << 2;
    return p * XROW + 2 * (cw ^ sw);
}

__global__ __launch_bounds__(256, 3) void proj_kernel(const float* __restrict__ x,
                                                      const u16* __restrict__ wh,
                                                      const float* __restrict__ bq,
                                                      const float* __restrict__ bk,
                                                      u16* __restrict__ q,
                                                      u16* __restrict__ k) {
    __shared__ __align__(16) u16 smem[9216];
    int b  = blockIdx.y;
    int p0 = blockIdx.x * 64;
    int tid = threadIdx.x;
    int lane = tid & 63, w = tid >> 6;
    int ln = lane & 15, g = lane >> 4;

    float biasv[4];
#pragma unroll
    for (int nf = 0; nf < 4; nf++) {
        int oc = w * 64 + nf * 16 + ln;
        biasv[nf] = (oc < 128) ? bq[oc] : bk[oc - 128];
    }

    f32x4 acc[4][4];
#pragma unroll
    for (int mf = 0; mf < 4; mf++)
#pragma unroll
        for (int nf = 0; nf < 4; nf++) acc[mf][nf] = 0.0f;

    int si  = tid >> 4;          // 0..15
    int spx = (tid & 15) * 4;

#define STAGE(buf, c0)                                                                  \
    {                                                                                   \
        const float* xa = x + ((size_t)(b * NC + (c0) + 2 * si)) * NHW + p0 + spx;      \
        const float* xb = xa + NHW;                                                     \
        float4 a0 = *(const float4*)xa;                                                 \
        float4 b0 = *(const float4*)xb;                                                 \
        float av[4] = {a0.x, a0.y, a0.z, a0.w};                                         \
        float bv[4] = {b0.x, b0.y, b0.z, b0.w};                                         \
        _Pragma("unroll") for (int j = 0; j < 4; j++) {                                 \
            ushort2 pk;                                                                 \
            pk.x = f2h(av[j]); pk.y = f2h(bv[j]);                                       \
            *(ushort2*)&smem[(buf) * 2560 + xt2_off(spx + j, si)] = pk;                 \
        }                                                                               \
    }

    STAGE(0, 0);
    __syncthreads();
    for (int t = 0; t < 16; ++t) {
        int c0 = t * 32;
        if (t < 15) STAGE((t + 1) & 1, c0 + 32);
        f16x8 bf[4];
#pragma unroll
        for (int nf = 0; nf < 4; nf++)
            bf[nf] = *(const f16x8*)&wh[((size_t)(w * 64 + nf * 16 + ln)) * NC + c0 + g * 8];
        f16x8 af[4];
#pragma unroll
        for (int mf = 0; mf < 4; mf++)
            af[mf] = *(const f16x8*)&smem[(t & 1) * 2560 + xt2_off(mf * 16 + ln, g * 4)];
#pragma unroll
        for (int mf = 0; mf < 4; mf++)
#pragma unroll
            for (int nf = 0; nf < 4; nf++)
                acc[mf][nf] = __builtin_amdgcn_mfma_f32_16x16x32_f16(af[mf], bf[nf], acc[mf][nf], 0, 0, 0);
        __syncthreads();
    }
#undef STAGE

#pragma unroll
    for (int pass = 0; pass < 2; pass++) {
        if ((w >> 1) == pass) {
            int colbase = (w & 1) * 64;
#pragma unroll
            for (int mf = 0; mf < 4; mf++)
#pragma unroll
                for (int nf = 0; nf < 4; nf++)
#pragma unroll
                    for (int rg = 0; rg < 4; rg++) {
                        int p = mf * 16 + g * 4 + rg;
                        smem[p * 136 + colbase + nf * 16 + ln] = f2h(acc[mf][nf][rg] + biasv[nf]);
                    }
        }
        __syncthreads();
        {
            int p = tid >> 2, seg = tid & 3;
            u16* dst = (pass == 0 ? q : k) + ((size_t)(b * NHW + p0 + p)) * NK + seg * 32;
            const u16* srcl = &smem[p * 136 + seg * 32];
            *(uint4*)(dst)     = *(const uint4*)(srcl);
            *(uint4*)(dst + 8) = *(const uint4*)(srcl + 8);
            *(uint4*)(dst + 16) = *(const uint4*)(srcl + 16);
            *(uint4*)(dst + 24) = *(const uint4*)(srcl + 24);
        }
        __syncthreads();
    }
}

// ---------------- axis attention via MFMA (v2: V double-buffered in regs) ----------------
// TR=0 (W-pass): r=h, Q/K rows contiguous, V = x fp32
// TR=1 (H-pass): r=w, Q/K rows strided,   V = xt fp16
// OH=1: output fp16 (u16*); OH=0: output fp32 (float*)
template <int TR, int OH>
__global__ __launch_bounds__(256) void attn_kernel(const u16* __restrict__ q,
                                                   const u16* __restrict__ k,
                                                   const void* __restrict__ vsrc,
                                                   void* __restrict__ osrc) {
    __shared__ __align__(16) u16 smem[2 * 128 * 136];
    __shared__ float redmax[256];
    __shared__ float redsum[256];
    u16* Ks = smem;
    u16* Qs = smem + 128 * 136;
    u16* Al = smem;
    u16* Vl = smem + 128 * 136;

    int r = blockIdx.x, b = blockIdx.y;
    int tid = threadIdx.x;
    int lane = tid & 63, w = tid >> 6;
    int ln = lane & 15, g = lane >> 4;

    const size_t base = TR ? ((size_t)b * NHW + r) * NK : ((size_t)b * NHW + (size_t)r * NP) * NK;
    const int qrs = TR ? NP * NK : NK;

    {
        int j = tid >> 1, hf = tid & 1;
        const u16* qp2 = q + base + (size_t)j * qrs + hf * 64;
        const u16* kp2 = k + base + (size_t)j * qrs + hf * 64;
#pragma unroll
        for (int e = 0; e < 8; e++) {
            *(uint4*)&Qs[j * 136 + hf * 64 + e * 8] = *(const uint4*)(qp2 + e * 8);
            *(uint4*)&Ks[j * 136 + hf * 64 + e * 8] = *(const uint4*)(kp2 + e * 8);
        }
    }
    __syncthreads();

    int wj = w >> 1, wi = w & 1;
    f32x4 e[4][4];
#pragma unroll
    for (int mf = 0; mf < 4; mf++)
#pragma unroll
        for (int nf = 0; nf < 4; nf++) e[mf][nf] = 0.0f;
#pragma unroll
    for (int ks = 0; ks < 4; ks++) {
        f16x8 qa[4], kb[4];
#pragma unroll
        for (int mf = 0; mf < 4; mf++)
            qa[mf] = *(const f16x8*)&Qs[(wj * 64 + mf * 16 + ln) * 136 + ks * 32 + g * 8];
#pragma unroll
        for (int nf = 0; nf < 4; nf++)
            kb[nf] = *(const f16x8*)&Ks[(wi * 64 + nf * 16 + ln) * 136 + ks * 32 + g * 8];
#pragma unroll
        for (int mf = 0; mf < 4; mf++)
#pragma unroll
            for (int nf = 0; nf < 4; nf++)
                e[mf][nf] = __builtin_amdgcn_mfma_f32_16x16x32_f16(qa[mf], kb[nf], e[mf][nf], 0, 0, 0);
    }

    float pm[4];
#pragma unroll
    for (int nf = 0; nf < 4; nf++) {
        pm[nf] = -3.0e38f;
#pragma unroll
        for (int mf = 0; mf < 4; mf++)
#pragma unroll
            for (int rg = 0; rg < 4; rg++) pm[nf] = fmaxf(pm[nf], e[mf][nf][rg]);
        pm[nf] = fmaxf(pm[nf], __shfl_xor(pm[nf], 16));
        pm[nf] = fmaxf(pm[nf], __shfl_xor(pm[nf], 32));
    }
    if (g == 0) {
#pragma unroll
        for (int nf = 0; nf < 4; nf++) redmax[wj * 128 + wi * 64 + nf * 16 + ln] = pm[nf];
    }
    __syncthreads();
    float fm[4];
#pragma unroll
    for (int nf = 0; nf < 4; nf++) {
        int i = wi * 64 + nf * 16 + ln;
        fm[nf] = fmaxf(redmax[i], redmax[128 + i]);
    }
    float ps[4] = {0.f, 0.f, 0.f, 0.f};
#pragma unroll
    for (int mf = 0; mf < 4; mf++)
#pragma unroll
        for (int nf = 0; nf < 4; nf++)
#pragma unroll
            for (int rg = 0; rg < 4; rg++) {
                float v = __expf(e[mf][nf][rg] - fm[nf]);
                e[mf][nf][rg] = v;
                ps[nf] += v;
            }
#pragma unroll
    for (int nf = 0; nf < 4; nf++) {
        ps[nf] += __shfl_xor(ps[nf], 16);
        ps[nf] += __shfl_xor(ps[nf], 32);
    }
    if (g == 0) {
#pragma unroll
        for (int nf = 0; nf < 4; nf++) redsum[wj * 128 + wi * 64 + nf * 16 + ln] = ps[nf];
    }
    __syncthreads();
    float ivs[4];
#pragma unroll
    for (int nf = 0; nf < 4; nf++) {
        int i = wi * 64 + nf * 16 + ln;
        ivs[nf] = 1.0f / (redsum[i] + redsum[128 + i]);
    }
#pragma unroll
    for (int mf = 0; mf < 4; mf++)
#pragma unroll
        for (int nf = 0; nf < 4; nf++) {
            ushort4 pk;
            pk.x = f2h(e[mf][nf][0] * ivs[nf]);
            pk.y = f2h(e[mf][nf][1] * ivs[nf]);
            pk.z = f2h(e[mf][nf][2] * ivs[nf]);
            pk.w = f2h(e[mf][nf][3] * ivs[nf]);
            *(ushort4*)&Al[(wi * 64 + nf * 16 + ln) * 136 + wj * 64 + mf * 16 + g * 4] = pk;
        }
    __syncthreads();

    int wc = w >> 1, wi2 = w & 1;
    f16x8 bfr[4][4];
#pragma unroll
    for (int nf2 = 0; nf2 < 4; nf2++)
#pragma unroll
        for (int js = 0; js < 4; js++)
            bfr[nf2][js] = *(const f16x8*)&Al[(wi2 * 64 + nf2 * 16 + ln) * 136 + js * 32 + g * 8];

    // ---- PV with register double-buffered V staging ----
    int cc = tid >> 2, ch = (tid & 3) * 32;
    u16 vh[32];
#define LOADV(c0)                                                                           \
    {                                                                                       \
        if (TR == 0) {                                                                      \
            const float* vn = (const float*)vsrc + ((size_t)(b * NC + (c0) + cc)) * NHW +   \
                              (size_t)r * NP + ch;                                          \
            _Pragma("unroll") for (int e2 = 0; e2 < 8; e2++) {                              \
                float4 vv = *(const float4*)(vn + e2 * 4);                                  \
                vh[e2 * 4 + 0] = f2h(vv.x); vh[e2 * 4 + 1] = f2h(vv.y);                     \
                vh[e2 * 4 + 2] = f2h(vv.z); vh[e2 * 4 + 3] = f2h(vv.w);                     \
            }                                                                               \
        } else {                                                                            \
            const u16* vn = (const u16*)vsrc + ((size_t)(b * NC + (c0) + cc)) * NHW +       \
                            (size_t)r * NP + ch;                                            \
            _Pragma("unroll") for (int e2 = 0; e2 < 4; e2++)                                \
                *(uint4*)&vh[e2 * 8] = *(const uint4*)(vn + e2 * 8);                        \
        }                                                                                   \
    }

    LOADV(0);
    for (int c0 = 0; c0 < NC; c0 += 64) {
#pragma unroll
        for (int e2 = 0; e2 < 4; e2++)
            *(uint4*)&Vl[cc * 136 + ch + e2 * 8] = *(uint4*)&vh[e2 * 8];
        __syncthreads();
        if (c0 + 64 < NC) LOADV(c0 + 64);   // hide next tile's HBM latency under MFMA
        f32x4 o[2][4];
#pragma unroll
        for (int mf2 = 0; mf2 < 2; mf2++)
#pragma unroll
            for (int nf2 = 0; nf2 < 4; nf2++) o[mf2][nf2] = 0.0f;
#pragma unroll
        for (int js = 0; js < 4; js++) {
            f16x8 va[2];
#pragma unroll
            for (int mf2 = 0; mf2 < 2; mf2++)
                va[mf2] = *(const f16x8*)&Vl[(wc * 32 + mf2 * 16 + ln) * 136 + js * 32 + g * 8];
#pragma unroll
            for (int mf2 = 0; mf2 < 2; mf2++)
#pragma unroll
                for (int nf2 = 0; nf2 < 4; nf2++)
                    o[mf2][nf2] = __builtin_amdgcn_mfma_f32_16x16x32_f16(va[mf2], bfr[nf2][js], o[mf2][nf2], 0, 0, 0);
        }
#pragma unroll
        for (int mf2 = 0; mf2 < 2; mf2++)
#pragma unroll
            for (int nf2 = 0; nf2 < 4; nf2++)
#pragma unroll
                for (int rg = 0; rg < 4; rg++) {
                    int ci = c0 + wc * 32 + mf2 * 16 + g * 4 + rg;
                    int ii = wi2 * 64 + nf2 * 16 + ln;
                    size_t oa = ((size_t)(b * NC + ci)) * NHW + (size_t)r * NP + ii;
                    if (OH) ((u16*)osrc)[oa] = f2h(o[mf2][nf2][rg]);
                    else    ((float*)osrc)[oa] = o[mf2][nf2][rg];
                }
        __syncthreads();
    }
#undef LOADV
}

// ---------------- out[plane][h][w] = owh[plane][h][w] + oht[plane][w][h] ----------------
__global__ __launch_bounds__(256) void combine_kernel(const u16* __restrict__ owh,
                                                      const u16* __restrict__ oht,
                                                      float* __restrict__ out) {
    __shared__ u16 ts[32][36];
    int plane = blockIdx.y;
    int tile  = blockIdx.x;
    int h0 = (tile >> 2) * 32, w0 = (tile & 3) * 32;
    int r  = threadIdx.x >> 3;
    int c4 = (threadIdx.x & 7) * 4;
    ushort4 v = *(const ushort4*)(oht + (size_t)plane * NHW + (w0 + r) * NP + h0 + c4);
    ts[r][c4 + 0] = v.x; ts[r][c4 + 1] = v.y; ts[r][c4 + 2] = v.z; ts[r][c4 + 3] = v.w;
    __syncthreads();
    ushort4 a = *(const ushort4*)(owh + (size_t)plane * NHW + (h0 + r) * NP + w0 + c4);
    float4 o;
    o.x = h2f(a.x) + h2f(ts[c4 + 0][r]);
    o.y = h2f(a.y) + h2f(ts[c4 + 1][r]);
    o.z = h2f(a.z) + h2f(ts[c4 + 2][r]);
    o.w = h2f(a.w) + h2f(ts[c4 + 3][r]);
    *(float4*)(out + (size_t)plane * NHW + (h0 + r) * NP + w0 + c4) = o;
}

// ---------------- fallback: out[plane][h][w] += oht[plane][w][h] (fp16 -> fp32 RMW) ----------------
__global__ __launch_bounds__(256) void addtr_kernel(const u16* __restrict__ oht,
                                                    float* __restrict__ out) {
    __shared__ u16 ts[32][36];
    int plane = blockIdx.y;
    int tile  = blockIdx.x;
    int h0 = (tile >> 2) * 32, w0 = (tile & 3) * 32;
    int r  = threadIdx.x >> 3;
    int c4 = (threadIdx.x & 7) * 4;
    ushort4 v = *(const ushort4*)(oht + (size_t)plane * NHW + (w0 + r) * NP + h0 + c4);
    ts[r][c4 + 0] = v.x; ts[r][c4 + 1] = v.y; ts[r][c4 + 2] = v.z; ts[r][c4 + 3] = v.w;
    __syncthreads();
    float* dst = out + (size_t)plane * NHW + (h0 + r) * NP + w0 + c4;
    float4 cur = *(const float4*)dst;
    cur.x += h2f(ts[c4 + 0][r]);
    cur.y += h2f(ts[c4 + 1][r]);
    cur.z += h2f(ts[c4 + 2][r]);
    cur.w += h2f(ts[c4 + 3][r]);
    *(float4*)dst = cur;
}

extern "C" void kernel_launch(void* const* d_in, const int* in_sizes, int n_in,
                              void* d_out, int out_size, void* d_ws, size_t ws_size,
                              hipStream_t stream) {
    const float* x  = (const float*)d_in[0];
    const float* wq = (const float*)d_in[1];
    const float* bq = (const float*)d_in[2];
    const float* wk = (const float*)d_in[3];
    const float* bk = (const float*)d_in[4];
    float* out = (float*)d_out;

    const size_t QKE = (size_t)NB * NHW * NK;  // 16,777,216 elems
    const size_t XE  = (size_t)NB * NC * NHW;  // 67,108,864 elems
    const size_t WHE = (size_t)256 * 512;
    u16* wh  = (u16*)d_ws;          // tiny, first
    u16* q   = wh + WHE;
    u16* k   = q + QKE;
    u16* xt  = k + QKE;
    u16* oht = xt + XE;
    u16* owh = oht + XE;            // only used if ws is big enough
    const size_t need_big = (WHE + 2 * QKE + 3 * XE) * sizeof(u16);  // ~470 MiB
    const bool big = ws_size >= need_big;

    dim3 blk(256);

    // 0. weights -> fp16
    wconv_kernel<<<dim3(256), blk, 0, stream>>>(wq, wk, wh);
    // 1. x -> xt fp16 transposed [b][c][w][h]
    convtr_kernel<<<dim3(16, NB * NC), blk, 0, stream>>>(x, xt);
    // 2. fused q,k projection (MFMA v3), pixel-major fp16
    proj_kernel<<<dim3(NHW / 64, NB), blk, 0, stream>>>(x, wh, bq, bk, q, k);
    // 3. H-attention -> oht fp16 [b][c][w][h]
    attn_kernel<1, 1><<<dim3(NP, NB), blk, 0, stream>>>(q, k, (const void*)xt, (void*)oht);
    if (big) {
        // 4. W-attention -> owh fp16; 5. out = owh + oht^T
        attn_kernel<0, 1><<<dim3(NP, NB), blk, 0, stream>>>(q, k, (const void*)x, (void*)owh);
        combine_kernel<<<dim3(16, NB * NC), blk, 0, stream>>>(owh, oht, out);
    } else {
        // fallback: W-attention -> out fp32, then RMW add of oht^T
        attn_kernel<0, 0><<<dim3(NP, NB), blk, 0, stream>>>(q, k, (const void*)x, (void*)out);
        addtr_kernel<<<dim3(16, NB * NC), blk, 0, stream>>>(oht, out);
    }
}